// Round 3
// baseline (487.508 us; speedup 1.0000x reference)
//
#include <hip/hip_runtime.h>
#include <hip/hip_bf16.h>

#define M_DIM 8192
#define N_DIM 4096
#define K_DIM 4096

typedef __attribute__((ext_vector_type(4))) int int4v;

// ---------------------------------------------------------------------------
// pack 4 rounded/clamped floats (as ints) into one int32 (little-endian bytes)
// ---------------------------------------------------------------------------
__device__ __forceinline__ int quant4(float4 v, float rs) {
    float r0 = rintf(v.x * rs), r1 = rintf(v.y * rs);
    float r2 = rintf(v.z * rs), r3 = rintf(v.w * rs);
    int i0 = (int)fminf(127.0f, fmaxf(-128.0f, r0));
    int i1 = (int)fminf(127.0f, fmaxf(-128.0f, r1));
    int i2 = (int)fminf(127.0f, fmaxf(-128.0f, r2));
    int i3 = (int)fminf(127.0f, fmaxf(-128.0f, r3));
    return (i0 & 255) | ((i1 & 255) << 8) | ((i2 & 255) << 16) | (i3 << 24);
}

__device__ __forceinline__ int pack4i(int4 v) {
    return (v.x & 255) | ((v.y & 255) << 8) | ((v.z & 255) << 16) | (v.w << 24);
}

// ---------------------------------------------------------------------------
// P1: blocks [0,1024): ternary int32 weight -> int8 (independent of absmax)
//     blocks [1024,3072): absmax of x -> amax (uint bits, |x| >= 0)
// ---------------------------------------------------------------------------
#define WCVT_BLOCKS 1024
#define ABS_BLOCKS 2048
__global__ void prep1_kernel(const float4* __restrict__ x,
                             const int4* __restrict__ w,
                             int* __restrict__ wq,
                             unsigned* __restrict__ amax) {
    if (blockIdx.x < WCVT_BLOCKS) {
        const int t = WCVT_BLOCKS * 256;
        const int n = (N_DIM * K_DIM) / 4;  // int4 count
        for (int i = blockIdx.x * 256 + threadIdx.x; i < n; i += 4 * t) {
            int4 a = w[i], b = w[i + t], c = w[i + 2 * t], d = w[i + 3 * t];
            wq[i] = pack4i(a);
            wq[i + t] = pack4i(b);
            wq[i + 2 * t] = pack4i(c);
            wq[i + 3 * t] = pack4i(d);
        }
    } else {
        const int t = ABS_BLOCKS * 256;
        const int n = (M_DIM * K_DIM) / 4;  // float4 count
        float m = 0.0f;
        for (int i = (blockIdx.x - WCVT_BLOCKS) * 256 + threadIdx.x; i < n;
             i += 4 * t) {
            float4 a = x[i], b = x[i + t], c = x[i + 2 * t], d = x[i + 3 * t];
            float ma = fmaxf(fmaxf(fabsf(a.x), fabsf(a.y)), fmaxf(fabsf(a.z), fabsf(a.w)));
            float mb = fmaxf(fmaxf(fabsf(b.x), fabsf(b.y)), fmaxf(fabsf(b.z), fabsf(b.w)));
            float mc = fmaxf(fmaxf(fabsf(c.x), fabsf(c.y)), fmaxf(fabsf(c.z), fabsf(c.w)));
            float md = fmaxf(fmaxf(fabsf(d.x), fabsf(d.y)), fmaxf(fabsf(d.z), fabsf(d.w)));
            m = fmaxf(m, fmaxf(fmaxf(ma, mb), fmaxf(mc, md)));
        }
        #pragma unroll
        for (int off = 32; off > 0; off >>= 1)
            m = fmaxf(m, __shfl_down(m, off, 64));
        __shared__ float sm[4];
        if ((threadIdx.x & 63) == 0) sm[threadIdx.x >> 6] = m;
        __syncthreads();
        if (threadIdx.x == 0) {
            float b = fmaxf(fmaxf(sm[0], sm[1]), fmaxf(sm[2], sm[3]));
            atomicMax(amax, __float_as_uint(b));
        }
    }
}

// ---------------------------------------------------------------------------
// P2: quantize x -> int8 (rintf = round-half-even = jnp.round, then clamp)
// ---------------------------------------------------------------------------
#define QUANT_BLOCKS 2048
__global__ void quant_kernel(const float4* __restrict__ x, int* __restrict__ q,
                             const unsigned* __restrict__ amax_u) {
    float amax = __uint_as_float(*amax_u);
    float scale = amax * (1.0f / 127.0f);
    if (scale == 0.0f) scale = 1.0f;
    const float rs = 1.0f / scale;
    const int t = QUANT_BLOCKS * 256;
    const int n = (M_DIM * K_DIM) / 4;  // float4 count (== int8x4 outputs)
    for (int i = blockIdx.x * 256 + threadIdx.x; i < n; i += 4 * t) {
        float4 a = x[i], b = x[i + t], c = x[i + 2 * t], d = x[i + 3 * t];
        q[i] = quant4(a, rs);
        q[i + t] = quant4(b, rs);
        q[i + 2 * t] = quant4(c, rs);
        q[i + 3 * t] = quant4(d, rs);
    }
}

// ---------------------------------------------------------------------------
// GEMM: i8, B-transposed. A:[M,K] i8, B:[N,K] i8, C:[M,N] f32.
//
// 256x128 tile, BK=64, 8 waves (4M x 2N -> 64x64 per wave),
// mfma_i32_16x16x64_i8. acc = 64 VGPR/wave -> total regs < 128 ->
// with 3 LDS buffers x 24 KB = 72 KB, TWO blocks co-resident per CU
// (4 waves/SIMD): while one block sits at its barrier/waitcnt, the other
// block's waves feed the matrix pipe. Counted 3-deep global_load_lds
// pipeline: stage tile u+2 during tile u, s_waitcnt vmcnt(3) per tile
// (never 0 until drain). ONE barrier per K-tile:
//   vmcnt(3) ; s_barrier ; ds_read 8 frags ; stage 3 loads ; 16 MFMA
// Hazards: own-stage confirmed by own vmcnt + barrier; WAR on the staged
// buffer is safe because every wave's reads of it completed (lgkm drain
// before MFMA issue) before that wave reached the barrier.
//
// LDS layout = gload-lds linear write order == fragment read order
// (lane*16B within 16-row x 64B segments) -> conflict-free ds_read_b128.
// ---------------------------------------------------------------------------
__device__ __forceinline__ void gload16(const char* g, char* l) {
    __builtin_amdgcn_global_load_lds(
        (const __attribute__((address_space(1))) unsigned int*)g,
        (__attribute__((address_space(3))) unsigned int*)l,
        16, 0, 0);
}

#define FENCE() asm volatile("" ::: "memory")
#define BAR()                                \
    do {                                     \
        FENCE();                             \
        __builtin_amdgcn_s_barrier();        \
        FENCE();                             \
    } while (0)

#define BUF_SZ 24576
#define LDS_SZ (3 * BUF_SZ)

__global__ __launch_bounds__(512, 4) void gemm_i8(
    const char* __restrict__ A,
    const char* __restrict__ B,
    float* __restrict__ C,
    const float* __restrict__ bias,
    const float* __restrict__ wscale,
    const unsigned* __restrict__ amax_u) {
    // 3 buffers x (A 16KB + B 8KB) = 72 KiB -> 2 blocks/CU
    __shared__ __align__(16) char L[LDS_SZ];

    // ---- XCD-aware tile swizzle: 1024 wgs, 8 XCDs, 8x16-tile patches ----
    // 32 M-tiles x 32 N-tiles. Patches: 4 along M (xcd>>1), 2 along N (xcd&1).
    const int f = blockIdx.x;
    const int xcd = f & 7;
    const int slot = f >> 3;      // 0..127
    const int sm = slot >> 4;     // 0..7
    int sn = slot & 15;
    if (sm & 1) sn = 15 - sn;     // serpentine
    const int mBase = ((xcd >> 1) * 8 + sm) * 256;
    const int nBase = ((xcd & 1) * 16 + sn) * 128;

    const int t = threadIdx.x;
    const int w = t >> 6;   // wave 0..7
    const int l = t & 63;
    const int lm = l & 15;
    const int lq = l >> 4;
    const int wm = w >> 1;  // 0..3  (M quarter: 64 rows)
    const int wn = w & 1;   // 0..1  (N half: 64 cols)

    // Staging roles: 3 slots/thread. Slots 0,1 = A segs {w, 8+w} (16 rows x
    // 64B each); slot 2 = B seg w. LDS: A at [0,16K), B at [16K,24K).
    const char* gpA0 = A + (size_t)(mBase + w * 16 + lm) * K_DIM + lq * 16;
    const char* gpA1 = gpA0 + (size_t)128 * K_DIM;
    const char* gpB  = B + (size_t)(nBase + w * 16 + lm) * K_DIM + lq * 16;
    const int loA0 = w * 1024;
    const int loA1 = (8 + w) * 1024;
    const int loB  = 16384 + w * 1024;

    #define STG(tt, bufoff)                                      \
    do {                                                         \
        gload16(gpA0 + (size_t)(tt) * 64, L + (bufoff) + loA0);  \
        gload16(gpA1 + (size_t)(tt) * 64, L + (bufoff) + loA1);  \
        gload16(gpB  + (size_t)(tt) * 64, L + (bufoff) + loB);   \
    } while (0)

    // ---- prologue: stage K-tiles 0 and 1 (6 loads/thread) ----
    STG(0, 0);
    STG(1, BUF_SZ);

    int4v acc[4][4];
    #pragma unroll
    for (int i = 0; i < 4; i++)
        #pragma unroll
        for (int j = 0; j < 4; j++)
            acc[i][j] = (int4v){0, 0, 0, 0};

    int cur = 0;            // buffer of tile u
    int curS = 2 * BUF_SZ;  // buffer of tile u+2 (stage target)

    // One K-tile: wait own stage of tile u -> barrier (now buf[u] globally
    // valid; also proves all reads of buf[(u+2)%3]'s previous contents are
    // done) -> read frags -> issue stage of u+2 -> 16 MFMA.
    #define KT(WSTR, DOSTG, u)                                              \
    do {                                                                    \
        asm volatile("s_waitcnt " WSTR ::: "memory");                       \
        BAR();                                                              \
        const char* aB = L + cur + wm * 4096 + l * 16;                      \
        const char* bB = L + cur + 16384 + wn * 4096 + l * 16;              \
        int4v af[4], bf[4];                                                 \
        _Pragma("unroll")                                                   \
        for (int r = 0; r < 4; ++r) af[r] = *(const int4v*)(aB + r * 1024); \
        _Pragma("unroll")                                                   \
        for (int c = 0; c < 4; ++c) bf[c] = *(const int4v*)(bB + c * 1024); \
        if (DOSTG) STG((u) + 2, curS);                                      \
        __builtin_amdgcn_s_setprio(1);                                      \
        _Pragma("unroll")                                                   \
        for (int r = 0; r < 4; ++r)                                         \
            _Pragma("unroll")                                               \
            for (int c = 0; c < 4; ++c)                                     \
                acc[r][c] = __builtin_amdgcn_mfma_i32_16x16x64_i8(          \
                    af[r], bf[c], acc[r][c], 0, 0, 0);                      \
        __builtin_amdgcn_s_setprio(0);                                      \
        cur += BUF_SZ;  if (cur == LDS_SZ) cur = 0;                         \
        curS += BUF_SZ; if (curS == LDS_SZ) curS = 0;                       \
    } while (0)

    // K tiles: 64. Stage u+2 for u<=61. vmcnt(3): at tile u, outstanding =
    // u's 3 + (u+1)'s 3; waiting to <=3 retires u's (in-order retire).
    #pragma unroll 1
    for (int u = 0; u < 63; ++u) {
        KT("vmcnt(3)", u <= 61, u);
    }
    KT("vmcnt(0)", false, 63);

    #undef KT
    #undef STG

    // ---- epilogue: scale + bias, same verified C/D mapping ----
    float amax = __uint_as_float(*amax_u);
    float scale = amax * (1.0f / 127.0f);
    if (scale == 0.0f) scale = 1.0f;
    const float s = wscale[0] * scale;

    #pragma unroll
    for (int ct = 0; ct < 4; ++ct) {
        const int col = nBase + wn * 64 + ct * 16 + lm;
        const float bb = bias[col];
        #pragma unroll
        for (int rt = 0; rt < 4; ++rt) {
            const int row0 = mBase + wm * 64 + rt * 16 + lq * 4;
            #pragma unroll
            for (int r = 0; r < 4; ++r) {
                C[(size_t)(row0 + r) * N_DIM + col] = (float)acc[rt][ct][r] * s + bb;
            }
        }
    }
}

// ---------------------------------------------------------------------------
extern "C" void kernel_launch(void* const* d_in, const int* in_sizes, int n_in,
                              void* d_out, int out_size, void* d_ws, size_t ws_size,
                              hipStream_t stream) {
    const float* x      = (const float*)d_in[0];   // [8192,4096] fp32
    const int* weight   = (const int*)d_in[1];     // [4096,4096] int32 ternary
    const float* wscale = (const float*)d_in[2];   // scalar
    const float* bias   = (const float*)d_in[3];   // [4096]
    float* out          = (float*)d_out;           // [8192,4096] fp32

    unsigned char* ws = (unsigned char*)d_ws;
    unsigned* amax = (unsigned*)ws;                             // 4 B
    char* Aq = (char*)(ws + 256);                               // M*K i8 = 32 MB
    char* Wb = (char*)(ws + 256 + (size_t)M_DIM * K_DIM);       // N*K i8 = 16 MB

    hipMemsetAsync(amax, 0, sizeof(unsigned), stream);

    prep1_kernel<<<WCVT_BLOCKS + ABS_BLOCKS, 256, 0, stream>>>(
        (const float4*)x, (const int4*)weight, (int*)Wb, amax);
    quant_kernel<<<QUANT_BLOCKS, 256, 0, stream>>>((const float4*)x, (int*)Aq, amax);

    gemm_i8<<<1024, 512, 0, stream>>>(Aq, Wb, out, bias, wscale, amax);
}